// Round 8
// baseline (310.452 us; speedup 1.0000x reference)
//
#include <hip/hip_runtime.h>

// Problem constants (B=16, T=512, N=2048, U=64) — all inputs/outputs FP32.
#define N_DIM 2048
#define U_DIM 64
#define M_DIM 8192   // B*T
#define K_DIM 2048   // = N

typedef __bf16 bf16x8 __attribute__((ext_vector_type(8)));
typedef float  floatx4 __attribute__((ext_vector_type(4)));
typedef float  floatx16 __attribute__((ext_vector_type(16)));
typedef unsigned short ushort8 __attribute__((ext_vector_type(8)));

#define AS1 __attribute__((address_space(1)))
#define AS3 __attribute__((address_space(3)))

__device__ __forceinline__ unsigned short f_to_bf16_rne(float f) {
    unsigned int x;
    __builtin_memcpy(&x, &f, 4);
    x += 0x7fffu + ((x >> 16) & 1u);
    return (unsigned short)(x >> 16);
}

// ---------------------------------------------------------------------------
// Kernel 1: wbar[k] = mean_i W[i,k]  (fp32), bmean = mean(b)
// ---------------------------------------------------------------------------
__global__ __launch_bounds__(256) void prep_kernel(
    const float* __restrict__ W, const float* __restrict__ b,
    float* __restrict__ wbar, float* __restrict__ bmean) {
    int k = blockIdx.x * 256 + threadIdx.x;
    float s = 0.f;
#pragma unroll
    for (int i = 0; i < U_DIM; ++i) s += W[i * N_DIM + k];
    wbar[k] = s * (1.f / U_DIM);

    if (blockIdx.x == 0 && threadIdx.x < 64) {
        float v = b[threadIdx.x];
#pragma unroll
        for (int off = 32; off > 0; off >>= 1) v += __shfl_down(v, off);
        if (threadIdx.x == 0) bmean[0] = v * (1.f / U_DIM);
    }
}

// ---------------------------------------------------------------------------
// Kernel 2 (merged): blocks [0, 2048): weff[j,k] = bf16(Adj[j,k]*wbar[k])
//                    blocks [2048, 10240): xbf = bf16(x)
// ---------------------------------------------------------------------------
__global__ __launch_bounds__(256) void weff_convx_kernel(
    const float* __restrict__ Adj, const float* __restrict__ wbar,
    unsigned short* __restrict__ weff,
    const float* __restrict__ x, unsigned short* __restrict__ xbf) {
    if (blockIdx.x < 2048) {
        long long idx = ((long long)blockIdx.x * 256 + threadIdx.x) * 8;
        int k = (int)(idx & (N_DIM - 1));
        floatx4 a0 = *(const floatx4*)(Adj + idx);
        floatx4 a1 = *(const floatx4*)(Adj + idx + 4);
        floatx4 w0 = *(const floatx4*)(wbar + k);
        floatx4 w1 = *(const floatx4*)(wbar + k + 4);
        ushort8 ov;
#pragma unroll
        for (int j = 0; j < 4; ++j) {
            ov[j]     = f_to_bf16_rne(a0[j] * w0[j]);
            ov[j + 4] = f_to_bf16_rne(a1[j] * w1[j]);
        }
        *(ushort8*)(weff + idx) = ov;
    } else {
        long long idx = ((long long)(blockIdx.x - 2048) * 256 + threadIdx.x) * 8;
        floatx4 a0 = *(const floatx4*)(x + idx);
        floatx4 a1 = *(const floatx4*)(x + idx + 4);
        ushort8 ov;
#pragma unroll
        for (int j = 0; j < 4; ++j) {
            ov[j]     = f_to_bf16_rne(a0[j]);
            ov[j + 4] = f_to_bf16_rne(a1[j]);
        }
        *(ushort8*)(xbf + idx) = ov;
    }
}

// Fallback converter for chunked path (small ws)
__global__ __launch_bounds__(256) void convx_kernel(
    const float* __restrict__ x, unsigned short* __restrict__ xbf) {
    long long idx = ((long long)blockIdx.x * 256 + threadIdx.x) * 8;
    floatx4 a0 = *(const floatx4*)(x + idx);
    floatx4 a1 = *(const floatx4*)(x + idx + 4);
    ushort8 ov;
#pragma unroll
    for (int j = 0; j < 4; ++j) {
        ov[j]     = f_to_bf16_rne(a0[j]);
        ov[j + 4] = f_to_bf16_rne(a1[j]);
    }
    *(ushort8*)(xbf + idx) = ov;
}

// ---------------------------------------------------------------------------
// Kernel 3: C[m,j] = sum_k A[m,k]*Bt[j,k] + bmean   (bf16 in, fp32 acc/out)
//
// R8 = R7 resubmitted verbatim (R7 died to the R1-signature container flake;
// source re-audited: barriers uniform, vmcnt FIFO audited, regs ~190<256).
//
// Structural change vs R6: DS pipe was the invariant critical path (R0-R6:
// 192 b128-reads + 64 KB writes ~ 3580 cyc/CU-tile vs MFMA 2048).
//  - B NEVER touches LDS: per-lane gather straight from global into a
//    2-deep STATIC register buffer (rb0/rb1, manual x2 unroll; rule #20).
//    B-panel per XCD = 1 MB (nt=id&7) -> L2-resident; lanes l,l+32 share
//    64-B lines; s-pairs re-hit L1.
//  - LDS holds only A: sA[2][128*64] = 32 KB; per-CU-tile DS drops to
//    64 b128-reads + 16 KB writes ~ 1150 cyc < MFMA 1024+overhead.
//  - block 128M x 256N, 8 waves (2M x 4N), wave tile 64x64 -> acc only
//    2x2 f32x16 = 64 VGPR; total ~190 regs, no spill at 2 waves/SIMD.
//
// vmcnt (audited): per tile issue [B(t+1) x8 loads, A(t+2) x2 gload_lds];
// steady-state wait vmcnt(2) (A(t+1) outstanding), final tile vmcnt(0).
// Prologue order B(0), A(0), A(1) matches.
// ---------------------------------------------------------------------------
#define BM 128
#define BN 256
#define BK 64
#define NT (K_DIM / BK)   // 32

__global__ __launch_bounds__(512, 2) void gemm_bt_kernel(
    const unsigned short* __restrict__ A,    // [M, K] bf16 bits (xbf)
    const unsigned short* __restrict__ Bt,   // [N, K] bf16 bits (weff)
    const float* __restrict__ bmeanp,
    float* __restrict__ C,                   // [M, N] fp32
    int mtiles) {
    __shared__ __align__(16) unsigned short sA[2][BM * BK];  // 2 x 16 KB

    const int id   = blockIdx.x;
    const int nt   = id & 7;        // n-tile == XCD (round-robin dispatch)
    const int mt   = id >> 3;
    const int tile_m = mt * BM;
    const int tile_n = nt * BN;

    const int tid  = threadIdx.x;
    const int w    = tid >> 6;      // wave 0..7
    const int lane = tid & 63;
    const int wm   = w >> 2;        // 0..1  (M split)
    const int wn   = w & 3;         // 0..3  (N split)

    const float bmean = bmeanp[0];

    // --- A staging: 16 chunks of 8 rows x 128 B; wave w stages chunks
    // 2w, 2w+1 (rows 16w..16w+15). lane l -> row l>>3, slot l&7; pre-swizzled
    // global chunk kc = (l&7)^(l>>3): LDS[r][slot] = G[r][slot ^ (r&7)].
    const int srow = lane >> 3;
    const int skc  = (lane & 7) ^ srow;
    const unsigned short* gA0 = A + (size_t)(tile_m + w * 16 + srow) * K_DIM + skc * 8;

    // --- A fragment addressing (32x32x16): row = base+ln31, k = hq*8+j;
    // K-step s -> chunk kc = s*2+hq, slot = kc ^ (row&7), row&7 = l7.
    const int ln31 = lane & 31;
    const int hq   = lane >> 5;     // 0..1
    const int l7   = lane & 7;
    int abase[2], slotk[4];
#pragma unroll
    for (int mi = 0; mi < 2; ++mi) abase[mi] = (wm * 64 + mi * 32 + ln31) * BK;
#pragma unroll
    for (int s = 0; s < 4; ++s)    slotk[s] = ((s * 2 + hq) ^ l7) * 8;

    // --- B direct-from-global: lane reads col = tile_n + wn*64 + ni*32 + ln31,
    // 16 B at k = t*BK + (s*2+hq)*8. 16-B aligned; lanes l,l+32 share a 64-B line.
    const unsigned short* pB[2];
#pragma unroll
    for (int ni = 0; ni < 2; ++ni)
        pB[ni] = Bt + (size_t)(tile_n + wn * 64 + ni * 32 + ln31) * K_DIM + hq * 8;

    floatx16 acc[2][2];
#pragma unroll
    for (int mi = 0; mi < 2; ++mi)
#pragma unroll
        for (int ni = 0; ni < 2; ++ni)
#pragma unroll
            for (int r = 0; r < 16; ++r) acc[mi][ni][r] = 0.f;

    #define STAGE_A(p, kt)                                                        \
        do {                                                                      \
            const int ko_ = (kt) * BK;                                            \
            _Pragma("unroll")                                                     \
            for (int i_ = 0; i_ < 2; ++i_) {                                      \
                __builtin_amdgcn_global_load_lds(                                 \
                    (const AS1 void*)(gA0 + ko_ + (size_t)i_ * 8 * K_DIM),        \
                    (AS3 void*)(&sA[(p)][(w * 2 + i_) * 8 * BK]), 16, 0, 0);      \
            }                                                                     \
        } while (0)

    #define LOADB(RB, kt)                                                         \
        do {                                                                      \
            _Pragma("unroll")                                                     \
            for (int ni_ = 0; ni_ < 2; ++ni_) {                                   \
                _Pragma("unroll")                                                 \
                for (int s_ = 0; s_ < 4; ++s_)                                    \
                    RB[ni_][s_] = *(const bf16x8*)(pB[ni_] + (kt) * BK + s_ * 16);\
            }                                                                     \
        } while (0)

    // rb dbuf: static names only (rule #20)
    bf16x8 rb0[2][4], rb1[2][4];

    // prologue: issue order B(0) [8], A(0) [2], A(1) [2]
    LOADB(rb0, 0);
    STAGE_A(0, 0);
    STAGE_A(1, 1);

    #define BODY(T, RBC, RBN)                                                     \
        do {                                                                      \
            const int t_ = (T);                                                   \
            const int p_ = t_ & 1;                                                \
            /* A(t) gload_lds + B(t) landed; A(t+1) stays outstanding */          \
            if (t_ == NT - 1) asm volatile("s_waitcnt vmcnt(0)" ::: "memory");    \
            else              asm volatile("s_waitcnt vmcnt(2)" ::: "memory");    \
            __builtin_amdgcn_s_barrier();  /* A(t) published */                   \
            if (t_ + 1 < NT) LOADB(RBN, t_ + 1);                                  \
            __builtin_amdgcn_sched_barrier(0);                                    \
            bf16x8 af[2][4];                                                      \
            _Pragma("unroll")                                                     \
            for (int mi_ = 0; mi_ < 2; ++mi_) {                                   \
                _Pragma("unroll")                                                 \
                for (int s_ = 0; s_ < 4; ++s_)                                    \
                    af[mi_][s_] =                                                 \
                        *(const bf16x8*)&sA[p_][abase[mi_] + slotk[s_]];          \
            }                                                                     \
            asm volatile("s_waitcnt lgkmcnt(0)" ::: "memory");                    \
            __builtin_amdgcn_sched_barrier(0);                                    \
            __builtin_amdgcn_s_setprio(1);                                        \
            _Pragma("unroll")                                                     \
            for (int s_ = 0; s_ < 4; ++s_) {                                      \
                _Pragma("unroll")                                                 \
                for (int mi_ = 0; mi_ < 2; ++mi_) {                               \
                    _Pragma("unroll")                                             \
                    for (int ni_ = 0; ni_ < 2; ++ni_)                             \
                        acc[mi_][ni_] =                                           \
                            __builtin_amdgcn_mfma_f32_32x32x16_bf16(              \
                                af[mi_][s_], RBC[ni_][s_], acc[mi_][ni_],         \
                                0, 0, 0);                                         \
                }                                                                 \
            }                                                                     \
            __builtin_amdgcn_s_setprio(0);                                        \
            __builtin_amdgcn_s_barrier();  /* sA[p_] free */                      \
            if (t_ + 2 < NT) STAGE_A(p_, t_ + 2);                                 \
            __builtin_amdgcn_sched_barrier(0);                                    \
        } while (0)

    for (int tt = 0; tt < NT; tt += 2) {
        BODY(tt,     rb0, rb1);
        BODY(tt + 1, rb1, rb0);
    }
    #undef BODY
    #undef LOADB
    #undef STAGE_A

    // Epilogue. 32x32 C/D: col = lane&31, row = (r&3)+8*(r>>2)+4*(lane>>5)
    // [m74/m101; convention validated by R6 pass]
    const int crow = tile_m + wm * 64 + hq * 4;
    const int ccol = tile_n + wn * 64 + ln31;
#pragma unroll
    for (int mi = 0; mi < 2; ++mi)
#pragma unroll
        for (int ni = 0; ni < 2; ++ni)
#pragma unroll
            for (int r = 0; r < 16; ++r) {
                int gm = crow + mi * 32 + (r & 3) + 8 * (r >> 2);
                int gn = ccol + ni * 32;
                C[(size_t)gm * N_DIM + gn] = acc[mi][ni][r] + bmean;
            }
    (void)mtiles;
}

// ---------------------------------------------------------------------------
extern "C" void kernel_launch(void* const* d_in, const int* in_sizes, int n_in,
                              void* d_out, int out_size, void* d_ws, size_t ws_size,
                              hipStream_t stream) {
    (void)in_sizes; (void)n_in; (void)out_size;
    const float* x   = (const float*)d_in[0];  // [16,512,2048]
    const float* Adj = (const float*)d_in[1];  // [2048,2048]
    const float* W   = (const float*)d_in[2];  // [64,2048]
    const float* b   = (const float*)d_in[3];  // [64]
    float* out = (float*)d_out;                // [16,512,2048] fp32

    // ws: wbar @0 (8 KB) | bmean @8192 | weff bf16 @16384 (8.39 MB) | xbf
    char* ws = (char*)d_ws;
    float* wbar  = (float*)ws;
    float* bmean = (float*)(ws + 8192);
    unsigned short* weff = (unsigned short*)(ws + 16384);
    const size_t weff_bytes = (size_t)N_DIM * N_DIM * 2;
    const size_t xbf_off = 16384 + weff_bytes;
    unsigned short* xbf = (unsigned short*)(ws + xbf_off);

    size_t avail = (ws_size > xbf_off) ? (ws_size - xbf_off) : 0;
    long long max_rows = (long long)(avail / ((size_t)K_DIM * 2)) / BM * BM;
    if (max_rows < BM) max_rows = BM;
    if (max_rows > M_DIM) max_rows = M_DIM;

    prep_kernel<<<N_DIM / 256, 256, 0, stream>>>(W, b, wbar, bmean);

    if (max_rows == M_DIM) {
        // full-size path: merged weff+convx, then A-LDS/B-reg GEMM
        weff_convx_kernel<<<2048 + M_DIM, 256, 0, stream>>>(Adj, wbar, weff, x, xbf);
        gemm_bt_kernel<<<(M_DIM / BM) * (N_DIM / BN), 512, 0, stream>>>(
            xbf, weff, bmean, out, M_DIM / BM);
    } else {
        weff_convx_kernel<<<2048, 256, 0, stream>>>(Adj, wbar, weff, x, xbf);
        for (long long m0 = 0; m0 < M_DIM; m0 += max_rows) {
            long long rows = (M_DIM - m0 < max_rows) ? (M_DIM - m0) : max_rows;
            convx_kernel<<<(int)rows, 256, 0, stream>>>(x + m0 * K_DIM, xbf);
            gemm_bt_kernel<<<(int)(rows / BM) * (N_DIM / BN), 512, 0, stream>>>(
                xbf, weff, bmean, out + m0 * (size_t)N_DIM, (int)(rows / BM));
        }
    }
}

// Round 9
// 231.412 us; speedup vs baseline: 1.3416x; 1.3416x over previous
//
#include <hip/hip_runtime.h>

// Problem constants (B=16, T=512, N=2048, U=64) — all inputs/outputs FP32.
#define N_DIM 2048
#define U_DIM 64
#define M_DIM 8192   // B*T
#define K_DIM 2048   // = N

typedef __bf16 bf16x8 __attribute__((ext_vector_type(8)));
typedef float  floatx4 __attribute__((ext_vector_type(4)));
typedef float  floatx16 __attribute__((ext_vector_type(16)));
typedef unsigned short ushort8 __attribute__((ext_vector_type(8)));
typedef unsigned short ushort4b __attribute__((ext_vector_type(4)));

#define AS1 __attribute__((address_space(1)))
#define AS3 __attribute__((address_space(3)))

__device__ __forceinline__ unsigned short f_to_bf16_rne(float f) {
    unsigned int x;
    __builtin_memcpy(&x, &f, 4);
    x += 0x7fffu + ((x >> 16) & 1u);
    return (unsigned short)(x >> 16);
}

// ---------------------------------------------------------------------------
// Kernel 1: wbar[k] = mean_i W[i,k]  (fp32), bmean = mean(b)
// ---------------------------------------------------------------------------
__global__ __launch_bounds__(256) void prep_kernel(
    const float* __restrict__ W, const float* __restrict__ b,
    float* __restrict__ wbar, float* __restrict__ bmean) {
    int k = blockIdx.x * 256 + threadIdx.x;
    float s = 0.f;
#pragma unroll
    for (int i = 0; i < U_DIM; ++i) s += W[i * N_DIM + k];
    wbar[k] = s * (1.f / U_DIM);

    if (blockIdx.x == 0 && threadIdx.x < 64) {
        float v = b[threadIdx.x];
#pragma unroll
        for (int off = 32; off > 0; off >>= 1) v += __shfl_down(v, off);
        if (threadIdx.x == 0) bmean[0] = v * (1.f / U_DIM);
    }
}

// ---------------------------------------------------------------------------
// Kernel 2: weff[j,k] = bf16(Adj[j,k]*wbar[k])   (x-conversion now fused
// into the GEMM's A-staging — the xbf intermediate is GONE)
// ---------------------------------------------------------------------------
__global__ __launch_bounds__(256) void weff_kernel(
    const float* __restrict__ Adj, const float* __restrict__ wbar,
    unsigned short* __restrict__ weff) {
    long long idx = ((long long)blockIdx.x * 256 + threadIdx.x) * 8;
    int k = (int)(idx & (N_DIM - 1));
    floatx4 a0 = *(const floatx4*)(Adj + idx);
    floatx4 a1 = *(const floatx4*)(Adj + idx + 4);
    floatx4 w0 = *(const floatx4*)(wbar + k);
    floatx4 w1 = *(const floatx4*)(wbar + k + 4);
    ushort8 ov;
#pragma unroll
    for (int j = 0; j < 4; ++j) {
        ov[j]     = f_to_bf16_rne(a0[j] * w0[j]);
        ov[j + 4] = f_to_bf16_rne(a1[j] * w1[j]);
    }
    *(ushort8*)(weff + idx) = ov;
}

// ---------------------------------------------------------------------------
// Kernel 3: C[m,j] = sum_k fp32->bf16(X[m,k]) * Bt[j,k] + bmean
//
// R9 = R6's verified GEMM core (256x256, BK=64, 8 waves, 32x32x16 MFMA,
// 4-cluster rotation) + FUSED A-conversion:
//  - A staged from fp32 X: global_load_dwordx4 x8 -> f_to_bf16_rne ->
//    swizzled ds_write_b64 x8 (T14 issue-early/write-late split).
//    Gather = 16 line-segments/instr (same as R6's staging; NOT R8's
//    32-line scatter). Removes the 96-MB xbf HBM round-trip + 8192 blocks.
//  - B staging unchanged (gload_lds, pre-swizzled, L2-resident per XCD).
//
// Sync per tile t (p=t&1):  [audited FIFO]
//   B1 ; issue Agld(t+2)x8 ; clusters 1-3 (R6) ; lgkm0 ; B2 ;
//   vmcnt(0) [drains Agld(t+2) + B(t+1), both >=1 tile old -> no stall] ;
//   cvt+ds_write A(t+2)->buf p ; gload_lds B(t+2)->buf p ; MFMA s=3 ; lgkm0
// Prologue: issue A(0)x8,A(1)x8,B(0)x4,B(1)x4; vmcnt 16/8/4 staged writes.
//
// A-write swizzle == read swizzle: LDS row R holds k-octet o at slot
// o^(R&7); write b64 halves at (o^arow)*8 + half*4 ushorts.
// ---------------------------------------------------------------------------
#define BM 256
#define BN 256
#define BK 64
#define NT (K_DIM / BK)   // 32

__global__ __launch_bounds__(512, 2) void gemm_bt_kernel(
    const float* __restrict__ X,             // [M, K] fp32 (raw x!)
    const unsigned short* __restrict__ Bt,   // [N, K] bf16 bits (weff)
    const float* __restrict__ bmeanp,
    float* __restrict__ C,                   // [M, N] fp32
    int mtiles) {
    __shared__ __align__(16) unsigned short sA[2][BM * BK];  // 2 x 32 KB
    __shared__ __align__(16) unsigned short sB[2][BN * BK];  // 2 x 32 KB

    const int id   = blockIdx.x;
    const int nt   = id & 7;        // n-tile == XCD (round-robin dispatch)
    const int mt   = id >> 3;
    const int tile_m = mt * BM;
    const int tile_n = nt * BN;

    const int tid  = threadIdx.x;
    const int w    = tid >> 6;      // wave 0..7
    const int lane = tid & 63;
    const int wm   = w >> 2;        // 0..1  (M split)
    const int wn   = w & 3;         // 0..3  (N split)

    const float bmean = bmeanp[0];

    // --- B staging (R6 verbatim): wave w stages chunks w*4..w*4+3.
    const int srow = lane >> 3;              // 0..7
    const int skc  = (lane & 7) ^ srow;
    const unsigned short* gB0 = Bt + (size_t)(tile_n + w * 32 + srow) * K_DIM + skc * 8;

    // --- A gather from fp32 X: wave w owns rows w*32..w*32+31 (4 chunks of 8).
    // lane l: row_in_chunk = l>>3, col-quad = l&7 (4 floats = 16 B).
    // instr h: cols h*32 + (l&7)*4  -> contiguous 128-B half-rows (16 seg/instr).
    const int arow = lane >> 3;     // 0..7
    const int acq  = lane & 7;      // 0..7
    const float* gX = X + (size_t)(tile_m + w * 32 + arow) * K_DIM + acq * 4;
    // write: half h holds k-octet o = h*4 + (acq>>1), half-within = acq&1.
    const unsigned awbase = (w * 32 + arow) * BK;   // + c*8*BK per chunk
    const unsigned awoff0 = (((acq >> 1)     ^ arow) * 8u) + (acq & 1) * 4u;
    const unsigned awoff1 = (((4 + (acq >> 1)) ^ arow) * 8u) + (acq & 1) * 4u;

    // --- fragment read addressing (R6 verbatim, 32x32x16).
    const int ln31 = lane & 31;
    const int hq   = lane >> 5;     // 0..1
    const int l7   = lane & 7;
    int abase[4], bbase[2], slotk[4];
#pragma unroll
    for (int mi = 0; mi < 4; ++mi) abase[mi] = (wm * 128 + mi * 32 + ln31) * BK;
#pragma unroll
    for (int ni = 0; ni < 2; ++ni) bbase[ni] = (wn * 64 + ni * 32 + ln31) * BK;
#pragma unroll
    for (int s = 0; s < 4; ++s)    slotk[s] = ((s * 2 + hq) ^ l7) * 8;

    floatx16 acc[4][2];
#pragma unroll
    for (int mi = 0; mi < 4; ++mi)
#pragma unroll
        for (int ni = 0; ni < 2; ++ni)
#pragma unroll
            for (int r = 0; r < 16; ++r) acc[mi][ni][r] = 0.f;

    #define STAGE_B(p, kt)                                                        \
        do {                                                                      \
            const int koff_ = (kt) * BK;                                          \
            _Pragma("unroll")                                                     \
            for (int i_ = 0; i_ < 4; ++i_) {                                      \
                __builtin_amdgcn_global_load_lds(                                 \
                    (const AS1 void*)(gB0 + koff_ + (size_t)i_ * 8 * K_DIM),      \
                    (AS3 void*)(&sB[(p)][(w * 4 + i_) * 8 * BK]), 16, 0, 0);      \
            }                                                                     \
        } while (0)

    #define AGLD(AV, kt)                                                          \
        do {                                                                      \
            _Pragma("unroll")                                                     \
            for (int c_ = 0; c_ < 4; ++c_) {                                      \
                AV[c_][0] = *(const floatx4*)(gX + (kt) * BK +                    \
                                              (size_t)c_ * 8 * K_DIM);            \
                AV[c_][1] = *(const floatx4*)(gX + (kt) * BK +                    \
                                              (size_t)c_ * 8 * K_DIM + 32);       \
            }                                                                     \
        } while (0)

    #define AWRITE(p, AV)                                                         \
        do {                                                                      \
            _Pragma("unroll")                                                     \
            for (int c_ = 0; c_ < 4; ++c_) {                                      \
                ushort4b t0_, t1_;                                                \
                _Pragma("unroll")                                                 \
                for (int j_ = 0; j_ < 4; ++j_) {                                  \
                    t0_[j_] = f_to_bf16_rne(AV[c_][0][j_]);                       \
                    t1_[j_] = f_to_bf16_rne(AV[c_][1][j_]);                       \
                }                                                                 \
                *(ushort4b*)&sA[(p)][awbase + c_ * 8 * BK + awoff0] = t0_;        \
                *(ushort4b*)&sA[(p)][awbase + c_ * 8 * BK + awoff1] = t1_;        \
            }                                                                     \
        } while (0)

    // ---- prologue: FIFO = [A0x8, A1x8, B0x4, B1x4]
    floatx4 av0[4][2], av1[4][2], av[4][2];
    AGLD(av0, 0);
    AGLD(av1, 1);
    STAGE_B(0, 0);
    STAGE_B(1, 1);
    asm volatile("s_waitcnt vmcnt(16)" ::: "memory");   // A0 landed
    __builtin_amdgcn_sched_barrier(0);
    AWRITE(0, av0);
    asm volatile("s_waitcnt vmcnt(8)" ::: "memory");    // A1 landed
    __builtin_amdgcn_sched_barrier(0);
    AWRITE(1, av1);
    asm volatile("s_waitcnt vmcnt(4)" ::: "memory");    // B0 landed (B1 in flight)
    asm volatile("s_waitcnt lgkmcnt(0)" ::: "memory");  // my ds_writes drained

    for (int t = 0; t < NT; ++t) {
        const int p = t & 1;

        __builtin_amdgcn_s_barrier();               // B1: buf p fully visible

        if (t + 2 < NT) AGLD(av, t + 2);            // issue-early (T14)
        __builtin_amdgcn_sched_barrier(0);

        bf16x8 b01[2][2], b23[2][2], a0[4], a1[4], a2[4], a3[4];

        // init burst: B s=0,1 + A s=0
#pragma unroll
        for (int ni = 0; ni < 2; ++ni)
#pragma unroll
            for (int s = 0; s < 2; ++s)
                b01[ni][s] = *(const bf16x8*)&sB[p][bbase[ni] + slotk[s]];
#pragma unroll
        for (int mi = 0; mi < 4; ++mi)
            a0[mi] = *(const bf16x8*)&sA[p][abase[mi] + slotk[0]];
        __builtin_amdgcn_sched_barrier(0);

        // ---- cluster 1: prefetch a1 + b23; MFMA s=0
#pragma unroll
        for (int mi = 0; mi < 4; ++mi)
            a1[mi] = *(const bf16x8*)&sA[p][abase[mi] + slotk[1]];
#pragma unroll
        for (int ni = 0; ni < 2; ++ni)
#pragma unroll
            for (int s = 0; s < 2; ++s)
                b23[ni][s] = *(const bf16x8*)&sB[p][bbase[ni] + slotk[2 + s]];
        __builtin_amdgcn_sched_barrier(0);
        __builtin_amdgcn_s_setprio(1);
#pragma unroll
        for (int mi = 0; mi < 4; ++mi)
#pragma unroll
            for (int ni = 0; ni < 2; ++ni)
                acc[mi][ni] = __builtin_amdgcn_mfma_f32_32x32x16_bf16(
                    a0[mi], b01[ni][0], acc[mi][ni], 0, 0, 0);
        __builtin_amdgcn_s_setprio(0);

        // ---- cluster 2: prefetch a2; MFMA s=1
#pragma unroll
        for (int mi = 0; mi < 4; ++mi)
            a2[mi] = *(const bf16x8*)&sA[p][abase[mi] + slotk[2]];
        __builtin_amdgcn_sched_barrier(0);
        __builtin_amdgcn_s_setprio(1);
#pragma unroll
        for (int mi = 0; mi < 4; ++mi)
#pragma unroll
            for (int ni = 0; ni < 2; ++ni)
                acc[mi][ni] = __builtin_amdgcn_mfma_f32_32x32x16_bf16(
                    a1[mi], b01[ni][1], acc[mi][ni], 0, 0, 0);
        __builtin_amdgcn_s_setprio(0);

        // ---- cluster 3: prefetch a3; MFMA s=2
#pragma unroll
        for (int mi = 0; mi < 4; ++mi)
            a3[mi] = *(const bf16x8*)&sA[p][abase[mi] + slotk[3]];
        __builtin_amdgcn_sched_barrier(0);
        __builtin_amdgcn_s_setprio(1);
#pragma unroll
        for (int mi = 0; mi < 4; ++mi)
#pragma unroll
            for (int ni = 0; ni < 2; ++ni)
                acc[mi][ni] = __builtin_amdgcn_mfma_f32_32x32x16_bf16(
                    a2[mi], b23[ni][0], acc[mi][ni], 0, 0, 0);
        __builtin_amdgcn_s_setprio(0);

        // ---- cluster 4: free buf p, restage tile t+2 into it, MFMA s=3
        asm volatile("s_waitcnt lgkmcnt(0)" ::: "memory");
        __builtin_amdgcn_sched_barrier(0);
        __builtin_amdgcn_s_barrier();               // B2: buf p free
        asm volatile("s_waitcnt vmcnt(0)" ::: "memory");   // av + B(t+1) landed
        __builtin_amdgcn_sched_barrier(0);
        if (t + 2 < NT) {
            AWRITE(p, av);                          // cvt + swizzled ds_write
            STAGE_B(p, t + 2);                      // gload_lds, in flight
        }
        __builtin_amdgcn_sched_barrier(0);
        __builtin_amdgcn_s_setprio(1);
#pragma unroll
        for (int mi = 0; mi < 4; ++mi)
#pragma unroll
            for (int ni = 0; ni < 2; ++ni)
                acc[mi][ni] = __builtin_amdgcn_mfma_f32_32x32x16_bf16(
                    a3[mi], b23[ni][1], acc[mi][ni], 0, 0, 0);
        __builtin_amdgcn_s_setprio(0);
        asm volatile("s_waitcnt lgkmcnt(0)" ::: "memory");  // my A-writes drained
    }
    #undef STAGE_B
    #undef AGLD
    #undef AWRITE

    // Epilogue. 32x32 C/D: col = lane&31, row = (r&3)+8*(r>>2)+4*(lane>>5)
    const int crow = tile_m + wm * 128 + hq * 4;
    const int ccol = tile_n + wn * 64 + ln31;
#pragma unroll
    for (int mi = 0; mi < 4; ++mi)
#pragma unroll
        for (int ni = 0; ni < 2; ++ni)
#pragma unroll
            for (int r = 0; r < 16; ++r) {
                int gm = crow + mi * 32 + (r & 3) + 8 * (r >> 2);
                int gn = ccol + ni * 32;
                C[(size_t)gm * N_DIM + gn] = acc[mi][ni][r] + bmean;
            }
    (void)mtiles;
}

// ---------------------------------------------------------------------------
extern "C" void kernel_launch(void* const* d_in, const int* in_sizes, int n_in,
                              void* d_out, int out_size, void* d_ws, size_t ws_size,
                              hipStream_t stream) {
    (void)in_sizes; (void)n_in; (void)out_size; (void)ws_size;
    const float* x   = (const float*)d_in[0];  // [16,512,2048]
    const float* Adj = (const float*)d_in[1];  // [2048,2048]
    const float* W   = (const float*)d_in[2];  // [64,2048]
    const float* b   = (const float*)d_in[3];  // [64]
    float* out = (float*)d_out;                // [16,512,2048] fp32

    // ws: wbar @0 (8 KB) | bmean @8192 | weff bf16 @16384 (8.39 MB)
    char* ws = (char*)d_ws;
    float* wbar  = (float*)ws;
    float* bmean = (float*)(ws + 8192);
    unsigned short* weff = (unsigned short*)(ws + 16384);

    prep_kernel<<<N_DIM / 256, 256, 0, stream>>>(W, b, wbar, bmean);
    weff_kernel<<<2048, 256, 0, stream>>>(Adj, wbar, weff);
    gemm_bt_kernel<<<(M_DIM / BM) * (N_DIM / BN), 512, 0, stream>>>(
        x, weff, bmean, out, M_DIM / BM);
}

// Round 10
// 220.399 us; speedup vs baseline: 1.4086x; 1.0500x over previous
//
#include <hip/hip_runtime.h>

// Problem constants (B=16, T=512, N=2048, U=64) — all inputs/outputs FP32.
#define N_DIM 2048
#define U_DIM 64
#define M_DIM 8192   // B*T
#define K_DIM 2048   // = N

typedef __bf16 bf16x8 __attribute__((ext_vector_type(8)));
typedef float  floatx4 __attribute__((ext_vector_type(4)));
typedef float  floatx16 __attribute__((ext_vector_type(16)));
typedef unsigned short ushort8 __attribute__((ext_vector_type(8)));

#define AS1 __attribute__((address_space(1)))
#define AS3 __attribute__((address_space(3)))

__device__ __forceinline__ unsigned short f_to_bf16_rne(float f) {
    unsigned int x;
    __builtin_memcpy(&x, &f, 4);
    x += 0x7fffu + ((x >> 16) & 1u);
    return (unsigned short)(x >> 16);
}

// ---------------------------------------------------------------------------
// Kernel 1: wbar[k] = mean_i W[i,k]  (fp32), bmean = mean(b)
// ---------------------------------------------------------------------------
__global__ __launch_bounds__(256) void prep_kernel(
    const float* __restrict__ W, const float* __restrict__ b,
    float* __restrict__ wbar, float* __restrict__ bmean) {
    int k = blockIdx.x * 256 + threadIdx.x;
    float s = 0.f;
#pragma unroll
    for (int i = 0; i < U_DIM; ++i) s += W[i * N_DIM + k];
    wbar[k] = s * (1.f / U_DIM);

    if (blockIdx.x == 0 && threadIdx.x < 64) {
        float v = b[threadIdx.x];
#pragma unroll
        for (int off = 32; off > 0; off >>= 1) v += __shfl_down(v, off);
        if (threadIdx.x == 0) bmean[0] = v * (1.f / U_DIM);
    }
}

// ---------------------------------------------------------------------------
// Kernel 2 (merged): blocks [0, 2048): weff[j,k] = bf16(Adj[j,k]*wbar[k])
//                    blocks [2048, 10240): xbf = bf16(x)
// NOTE (R9 post-mortem): the xbf bf16 intermediate SAVES HBM/L3 traffic —
// every A-panel is re-read by 8 XCDs; bf16 halves that footprint. Keep it.
// ---------------------------------------------------------------------------
__global__ __launch_bounds__(256) void weff_convx_kernel(
    const float* __restrict__ Adj, const float* __restrict__ wbar,
    unsigned short* __restrict__ weff,
    const float* __restrict__ x, unsigned short* __restrict__ xbf) {
    if (blockIdx.x < 2048) {
        long long idx = ((long long)blockIdx.x * 256 + threadIdx.x) * 8;
        int k = (int)(idx & (N_DIM - 1));
        floatx4 a0 = *(const floatx4*)(Adj + idx);
        floatx4 a1 = *(const floatx4*)(Adj + idx + 4);
        floatx4 w0 = *(const floatx4*)(wbar + k);
        floatx4 w1 = *(const floatx4*)(wbar + k + 4);
        ushort8 ov;
#pragma unroll
        for (int j = 0; j < 4; ++j) {
            ov[j]     = f_to_bf16_rne(a0[j] * w0[j]);
            ov[j + 4] = f_to_bf16_rne(a1[j] * w1[j]);
        }
        *(ushort8*)(weff + idx) = ov;
    } else {
        long long idx = ((long long)(blockIdx.x - 2048) * 256 + threadIdx.x) * 8;
        floatx4 a0 = *(const floatx4*)(x + idx);
        floatx4 a1 = *(const floatx4*)(x + idx + 4);
        ushort8 ov;
#pragma unroll
        for (int j = 0; j < 4; ++j) {
            ov[j]     = f_to_bf16_rne(a0[j]);
            ov[j + 4] = f_to_bf16_rne(a1[j]);
        }
        *(ushort8*)(xbf + idx) = ov;
    }
}

// Fallback converter for chunked path (small ws)
__global__ __launch_bounds__(256) void convx_kernel(
    const float* __restrict__ x, unsigned short* __restrict__ xbf) {
    long long idx = ((long long)blockIdx.x * 256 + threadIdx.x) * 8;
    floatx4 a0 = *(const floatx4*)(x + idx);
    floatx4 a1 = *(const floatx4*)(x + idx + 4);
    ushort8 ov;
#pragma unroll
    for (int j = 0; j < 4; ++j) {
        ov[j]     = f_to_bf16_rne(a0[j]);
        ov[j + 4] = f_to_bf16_rne(a1[j]);
    }
    *(ushort8*)(xbf + idx) = ov;
}

// ---------------------------------------------------------------------------
// Kernel 3: C[m,j] = sum_k A[m,k]*Bt[j,k] + bmean   (bf16 in, fp32 acc/out)
//
// R10 = R6 verbatim (best verified GEMM: 78.2 µs, MfmaUtil 36%).
// 256x256 tile, BK=64, 8 waves (2M x 4N), 32x32x16 MFMA, 4-cluster rotation,
// XOR-swizzled LDS, vmcnt(8) 2-deep counted pipeline, XCD mapping nt=id&7.
//
// Session ledger (why this config): five sync schedules (2-barrier/counted-
// vmcnt/4-cluster/8-phase/32x32) all land 78-87 µs — LDS pipe (~2048 cyc)
// and MFMA pipe (~2064 cyc) are co-critical per CU-K-tile at this geometry;
// B-direct-from-global (R5/R8) loses 2x to per-lane gather serialization;
// fused fp32-A staging (R9) loses via doubled XCD re-read traffic.
// ---------------------------------------------------------------------------
#define BM 256
#define BN 256
#define BK 64
#define NT (K_DIM / BK)   // 32

__global__ __launch_bounds__(512, 2) void gemm_bt_kernel(
    const unsigned short* __restrict__ A,    // [M, K] bf16 bits (xbf)
    const unsigned short* __restrict__ Bt,   // [N, K] bf16 bits (weff)
    const float* __restrict__ bmeanp,
    float* __restrict__ C,                   // [M, N] fp32
    int mtiles) {
    __shared__ __align__(16) unsigned short sA[2][BM * BK];  // 2 x 32 KB
    __shared__ __align__(16) unsigned short sB[2][BN * BK];  // 2 x 32 KB

    const int id   = blockIdx.x;
    const int nt   = id & 7;        // n-tile == XCD (round-robin dispatch)
    const int mt   = id >> 3;
    const int tile_m = mt * BM;
    const int tile_n = nt * BN;

    const int tid  = threadIdx.x;
    const int w    = tid >> 6;      // wave 0..7
    const int lane = tid & 63;
    const int wm   = w >> 2;        // 0..1  (M split)
    const int wn   = w & 3;         // 0..3  (N split)

    const float bmean = bmeanp[0];

    // --- staging: wave w stages A/B chunks [w*4, w*4+4).
    // chunk = 8 rows x 128 B. lane l -> row l>>3, LDS slot l&7; pre-swizzled
    // global chunk kc = (l&7)^(l>>3): LDS[r][slot] = G[r][slot ^ (r&7)].
    const int srow = lane >> 3;
    const int skc  = (lane & 7) ^ srow;
    const unsigned short* gA0 = A  + (size_t)(tile_m + w * 32 + srow) * K_DIM + skc * 8;
    const unsigned short* gB0 = Bt + (size_t)(tile_n + w * 32 + srow) * K_DIM + skc * 8;

    // --- 32x32x16 fragment addressing. A: row=lane&31, k=(lane>>5)*8+j;
    // K-step s (of 4) -> chunk kc = s*2 + (lane>>5); slot = kc ^ (row&7),
    // row&7 == lane&7 for every fragment row (bases are multiples of 32).
    const int ln31 = lane & 31;
    const int hq   = lane >> 5;     // 0..1
    const int l7   = lane & 7;
    int abase[4], bbase[2], slotk[4];
#pragma unroll
    for (int mi = 0; mi < 4; ++mi) abase[mi] = (wm * 128 + mi * 32 + ln31) * BK;
#pragma unroll
    for (int ni = 0; ni < 2; ++ni) bbase[ni] = (wn * 64 + ni * 32 + ln31) * BK;
#pragma unroll
    for (int s = 0; s < 4; ++s)    slotk[s] = ((s * 2 + hq) ^ l7) * 8;

    floatx16 acc[4][2];
#pragma unroll
    for (int mi = 0; mi < 4; ++mi)
#pragma unroll
        for (int ni = 0; ni < 2; ++ni)
#pragma unroll
            for (int r = 0; r < 16; ++r) acc[mi][ni][r] = 0.f;

    #define STAGE(p, kt)                                                          \
        do {                                                                      \
            const int koff_ = (kt) * BK;                                          \
            _Pragma("unroll")                                                     \
            for (int i_ = 0; i_ < 4; ++i_) {                                      \
                __builtin_amdgcn_global_load_lds(                                 \
                    (const AS1 void*)(gA0 + koff_ + (size_t)i_ * 8 * K_DIM),      \
                    (AS3 void*)(&sA[(p)][(w * 4 + i_) * 8 * BK]), 16, 0, 0);      \
                __builtin_amdgcn_global_load_lds(                                 \
                    (const AS1 void*)(gB0 + koff_ + (size_t)i_ * 8 * K_DIM),      \
                    (AS3 void*)(&sB[(p)][(w * 4 + i_) * 8 * BK]), 16, 0, 0);      \
            }                                                                     \
        } while (0)

    // prologue: tiles 0 and 1 in flight (16 outstanding per wave)
    STAGE(0, 0);
    STAGE(1, 1);

    for (int t = 0; t < NT; ++t) {
        const int p = t & 1;

        // tile t's 8 loads (oldest 8 of <=16) landed; newer 8 stay in flight.
        if (t == NT - 1) asm volatile("s_waitcnt vmcnt(0)" ::: "memory");
        else             asm volatile("s_waitcnt vmcnt(8)" ::: "memory");
        __builtin_amdgcn_s_barrier();               // B1: tile t visible

        bf16x8 b01[2][2], b23[2][2], a0[4], a1[4], a2[4], a3[4];

        // init burst: B s=0,1 + A s=0 (the only exposed LDS latency per tile)
#pragma unroll
        for (int ni = 0; ni < 2; ++ni)
#pragma unroll
            for (int s = 0; s < 2; ++s)
                b01[ni][s] = *(const bf16x8*)&sB[p][bbase[ni] + slotk[s]];
#pragma unroll
        for (int mi = 0; mi < 4; ++mi)
            a0[mi] = *(const bf16x8*)&sA[p][abase[mi] + slotk[0]];
        __builtin_amdgcn_sched_barrier(0);

        // ---- cluster 1: prefetch a1 + b23; MFMA s=0
#pragma unroll
        for (int mi = 0; mi < 4; ++mi)
            a1[mi] = *(const bf16x8*)&sA[p][abase[mi] + slotk[1]];
#pragma unroll
        for (int ni = 0; ni < 2; ++ni)
#pragma unroll
            for (int s = 0; s < 2; ++s)
                b23[ni][s] = *(const bf16x8*)&sB[p][bbase[ni] + slotk[2 + s]];
        __builtin_amdgcn_sched_barrier(0);
        __builtin_amdgcn_s_setprio(1);
#pragma unroll
        for (int mi = 0; mi < 4; ++mi)
#pragma unroll
            for (int ni = 0; ni < 2; ++ni)
                acc[mi][ni] = __builtin_amdgcn_mfma_f32_32x32x16_bf16(
                    a0[mi], b01[ni][0], acc[mi][ni], 0, 0, 0);
        __builtin_amdgcn_s_setprio(0);

        // ---- cluster 2: prefetch a2; MFMA s=1
#pragma unroll
        for (int mi = 0; mi < 4; ++mi)
            a2[mi] = *(const bf16x8*)&sA[p][abase[mi] + slotk[2]];
        __builtin_amdgcn_sched_barrier(0);
        __builtin_amdgcn_s_setprio(1);
#pragma unroll
        for (int mi = 0; mi < 4; ++mi)
#pragma unroll
            for (int ni = 0; ni < 2; ++ni)
                acc[mi][ni] = __builtin_amdgcn_mfma_f32_32x32x16_bf16(
                    a1[mi], b01[ni][1], acc[mi][ni], 0, 0, 0);
        __builtin_amdgcn_s_setprio(0);

        // ---- cluster 3: prefetch a3; MFMA s=2
#pragma unroll
        for (int mi = 0; mi < 4; ++mi)
            a3[mi] = *(const bf16x8*)&sA[p][abase[mi] + slotk[3]];
        __builtin_amdgcn_sched_barrier(0);
        __builtin_amdgcn_s_setprio(1);
#pragma unroll
        for (int mi = 0; mi < 4; ++mi)
#pragma unroll
            for (int ni = 0; ni < 2; ++ni)
                acc[mi][ni] = __builtin_amdgcn_mfma_f32_32x32x16_bf16(
                    a2[mi], b23[ni][0], acc[mi][ni], 0, 0, 0);
        __builtin_amdgcn_s_setprio(0);

        // ---- cluster 4: drain my reads, free buf p, stage t+2, MFMA s=3
        asm volatile("s_waitcnt lgkmcnt(0)" ::: "memory");
        __builtin_amdgcn_sched_barrier(0);
        __builtin_amdgcn_s_barrier();               // B2: buf p free
        if (t + 2 < NT) STAGE(p, t + 2);
        __builtin_amdgcn_sched_barrier(0);
        __builtin_amdgcn_s_setprio(1);
#pragma unroll
        for (int mi = 0; mi < 4; ++mi)
#pragma unroll
            for (int ni = 0; ni < 2; ++ni)
                acc[mi][ni] = __builtin_amdgcn_mfma_f32_32x32x16_bf16(
                    a3[mi], b23[ni][1], acc[mi][ni], 0, 0, 0);
        __builtin_amdgcn_s_setprio(0);
    }
    #undef STAGE

    // Epilogue. 32x32 C/D: col = lane&31, row = (r&3)+8*(r>>2)+4*(lane>>5)
    // [m74/m101; validated by R6 pass]
    const int crow = tile_m + wm * 128 + hq * 4;
    const int ccol = tile_n + wn * 64 + ln31;
#pragma unroll
    for (int mi = 0; mi < 4; ++mi)
#pragma unroll
        for (int ni = 0; ni < 2; ++ni)
#pragma unroll
            for (int r = 0; r < 16; ++r) {
                int gm = crow + mi * 32 + (r & 3) + 8 * (r >> 2);
                int gn = ccol + ni * 32;
                C[(size_t)gm * N_DIM + gn] = acc[mi][ni][r] + bmean;
            }
    (void)mtiles;
}

// ---------------------------------------------------------------------------
extern "C" void kernel_launch(void* const* d_in, const int* in_sizes, int n_in,
                              void* d_out, int out_size, void* d_ws, size_t ws_size,
                              hipStream_t stream) {
    (void)in_sizes; (void)n_in; (void)out_size;
    const float* x   = (const float*)d_in[0];  // [16,512,2048]
    const float* Adj = (const float*)d_in[1];  // [2048,2048]
    const float* W   = (const float*)d_in[2];  // [64,2048]
    const float* b   = (const float*)d_in[3];  // [64]
    float* out = (float*)d_out;                // [16,512,2048] fp32

    // ws: wbar @0 (8 KB) | bmean @8192 | weff bf16 @16384 (8.39 MB) | xbf
    char* ws = (char*)d_ws;
    float* wbar  = (float*)ws;
    float* bmean = (float*)(ws + 8192);
    unsigned short* weff = (unsigned short*)(ws + 16384);
    const size_t weff_bytes = (size_t)N_DIM * N_DIM * 2;
    const size_t xbf_off = 16384 + weff_bytes;
    unsigned short* xbf = (unsigned short*)(ws + xbf_off);

    size_t avail = (ws_size > xbf_off) ? (ws_size - xbf_off) : 0;
    long long max_rows = (long long)(avail / ((size_t)K_DIM * 2)) / BM * BM;
    if (max_rows < BM) max_rows = BM;
    if (max_rows > M_DIM) max_rows = M_DIM;

    prep_kernel<<<N_DIM / 256, 256, 0, stream>>>(W, b, wbar, bmean);

    if (max_rows == M_DIM) {
        // full-size path: merged weff+convx, then one 256^2 8-wave GEMM
        weff_convx_kernel<<<2048 + M_DIM, 256, 0, stream>>>(Adj, wbar, weff, x, xbf);
        gemm_bt_kernel<<<(M_DIM / BM) * (N_DIM / BN), 512, 0, stream>>>(
            xbf, weff, bmean, out, M_DIM / BM);
    } else {
        weff_convx_kernel<<<2048, 256, 0, stream>>>(Adj, wbar, weff, x, xbf);
        for (long long m0 = 0; m0 < M_DIM; m0 += max_rows) {
            long long rows = (M_DIM - m0 < max_rows) ? (M_DIM - m0) : max_rows;
            convx_kernel<<<(int)rows, 256, 0, stream>>>(x + m0 * K_DIM, xbf);
            gemm_bt_kernel<<<(int)(rows / BM) * (N_DIM / BN), 512, 0, stream>>>(
                xbf, weff, bmean, out + m0 * (size_t)N_DIM, (int)(rows / BM));
        }
    }
}